// Round 1
// baseline (230.987 us; speedup 1.0000x reference)
//
#include <hip/hip_runtime.h>

#define EPS 1e-8f
#define THREADS 512

typedef __attribute__((ext_vector_type(8))) short short8;
typedef __attribute__((ext_vector_type(4))) float f32x4;
typedef __attribute__((ext_vector_type(8))) unsigned short u16x8;

static __device__ __forceinline__ unsigned short f2bf(float f) {
  unsigned int u = __float_as_uint(f);
  u += 0x7FFF + ((u >> 16) & 1);   // round-to-nearest-even
  return (unsigned short)(u >> 16);
}

// ---------- K0: s[b,ci] = style[b,:] @ mod_weight[ci,:] + mod_bias[ci] ----------
__global__ void k_style(const float* __restrict__ style, const float* __restrict__ mw,
                        const float* __restrict__ mb, float* __restrict__ s_out) {
  int b = blockIdx.x, t = threadIdx.x;
  __shared__ float st[512];
  st[t]       = style[b*512 + t];
  st[t + 256] = style[b*512 + 256 + t];
  __syncthreads();
  const float4* row = (const float4*)(mw + (size_t)t*512);
  float acc = 0.f;
#pragma unroll 4
  for (int i = 0; i < 128; ++i) {
    float4 m = row[i];
    acc += m.x*st[4*i] + m.y*st[4*i+1] + m.z*st[4*i+2] + m.w*st[4*i+3];
  }
  s_out[b*256 + t] = acc + mb[t];
}

// ---------- K1: wsq[co,ci] = sum_r W^2 ; wbf = bf16 W in pre-swizzled panel layout ----------
// panel (c = ci>>6, r): 256 rows (co) x 64 ci, byte addr = (co*128 + cil*2) ^ ((co&7)<<4)
__global__ void k_wprep(const float* __restrict__ weight, float* __restrict__ wsq,
                        unsigned short* __restrict__ wbf) {
  int idx = blockIdx.x*256 + threadIdx.x;   // idx = co*256 + ci
  int co = idx >> 8, ci = idx & 255;
  const float* wp = weight + (size_t)idx*9;
  int c = ci >> 6, cil = ci & 63;
  int base = ((co*128 + cil*2) ^ ((co & 7) << 4)) >> 1;   // short index within 16384-short panel
  float sum = 0.f;
#pragma unroll
  for (int r = 0; r < 9; ++r) {
    float v = wp[r];
    sum += v*v;
    wbf[(size_t)(c*9 + r)*16384 + base] = f2bf(v);
  }
  wsq[idx] = sum;
}

// ---------- K2: demod[b,co] = rsqrt(sum_ci wsq[co,ci]*s[b,ci]^2 + eps) ----------
__global__ void k_demod(const float* __restrict__ s, const float* __restrict__ wsq,
                        float* __restrict__ dm) {
  int b = blockIdx.x, t = threadIdx.x;
  __shared__ float s2[256];
  float sv = s[b*256 + t];
  s2[t] = sv*sv;
  __syncthreads();
  const float4* row = (const float4*)(wsq + (size_t)t*256);
  float acc = 0.f;
#pragma unroll 4
  for (int i = 0; i < 64; ++i) {
    float4 q = row[i];
    acc += q.x*s2[4*i] + q.y*s2[4*i+1] + q.z*s2[4*i+2] + q.w*s2[4*i+3];
  }
  dm[b*256 + t] = rsqrtf(acc + EPS);
}

// ---------- K3: xp[b][gh][gw][ci] = bf16( x[b][ci][gh-1][gw-1] * s[b][ci] ), zero-padded ----------
__global__ void k_pad(const float* __restrict__ x, const float* __restrict__ s,
                      unsigned short* __restrict__ xp) {
  int bid = blockIdx.x;
  int b = bid / 66, gh = bid - b*66;
  int t = threadIdx.x;
  size_t rowbase = (size_t)(b*66 + gh) * (66*256);
  u16x8* rp = (u16x8*)(xp + rowbase);
  if (gh == 0 || gh == 65) {
    u16x8 z = (u16x8)0;
    for (int q = t; q < 2112; q += 256) rp[q] = z;
    return;
  }
  int h = gh - 1;
  __shared__ float sl[256];
  __shared__ unsigned short xl[64*256];   // [w][ci] bf16, 16B-slot swizzled by (w&31)
  sl[t] = s[b*256 + t];
  __syncthreads();
  int w = t & 63, cq = t >> 6;
#pragma unroll 4
  for (int c0 = 0; c0 < 256; c0 += 4) {
    int ci = c0 + cq;
    float v = x[((size_t)(b*256 + ci)*64 + h)*64 + w] * sl[ci];
    int byte = w*512 + (((ci >> 3) ^ (w & 31)) << 4) + (ci & 7)*2;
    xl[byte >> 1] = f2bf(v);
  }
  __syncthreads();
  u16x8 z = (u16x8)0;
  if (t < 32) rp[t] = z;                       // gw = 0 pad column
  else if (t < 64) rp[65*32 + (t - 32)] = z;   // gw = 65 pad column
  for (int q = t; q < 2048; q += 256) {
    int w2 = q >> 5, slot = q & 31;
    u16x8 v = *(const u16x8*)&xl[(w2*512 + ((slot ^ (w2 & 31)) << 4)) >> 1];
    rp[(w2 + 1)*32 + slot] = v;
  }
}

// ---------- K4: the conv as implicit GEMM ----------
// grid 256 = 16 b x 16 h-tiles; block computes 256co x (4h x 64w).
// 8 waves: wm = wave>>1 (64 co), wn = wave&1 (2 h rows x 64 w = 128 n).
__global__ __launch_bounds__(512, 2)
void k_conv(const unsigned short* __restrict__ xp, const unsigned short* __restrict__ wbf,
            const float* __restrict__ dm, const float* __restrict__ bias,
            float* __restrict__ out) {
  __shared__ unsigned short x_lds[6*66*64];   // 50688 B, row = hl*66+gw, 64 ci, XOR-swizzled
  __shared__ unsigned short w_lds[256*64];    // 32768 B, row = co, 64 ci, XOR-swizzled

  const int tid = threadIdx.x;
  const int lane = tid & 63;
  const int wave = tid >> 6;
  const int b = blockIdx.x >> 4;
  const int h0 = (blockIdx.x & 15) * 4;
  const int wm = wave >> 1, wn = wave & 1;
  const int l15 = lane & 15, lk = lane >> 4;

  f32x4 acc[4][8];
#pragma unroll
  for (int m = 0; m < 4; ++m)
#pragma unroll
    for (int f = 0; f < 8; ++f) acc[m][f] = (f32x4)0.f;

  for (int c = 0; c < 4; ++c) {
    __syncthreads();   // previous chunk's LDS reads complete
    {
      // stage x tile: 6 rows x 66 gw x 64 ci bf16 = 3168 16B chunks
      int cb = c*64;
      for (int it = 0; it < 7; ++it) {
        int q = it*THREADS + tid;
        if (q < 3168) {
          int hw = q >> 3;
          int hl = hw / 66, w = hw - hl*66;
          int slot = (q & 7) ^ (hw & 7);
          const unsigned short* src =
              xp + (size_t)((b*66 + h0 + hl)*66 + w)*256 + cb + slot*8;
          __builtin_amdgcn_global_load_lds(
              (const __attribute__((address_space(1))) void*)src,
              (__attribute__((address_space(3))) void*)&x_lds[(size_t)q*8],
              16, 0, 0);
        }
      }
    }
    for (int r = 0; r < 9; ++r) {
      if (r) __syncthreads();   // previous r's w_lds reads complete
      {
        const unsigned short* wsrc = wbf + (size_t)(c*9 + r)*16384;  // pre-swizzled, linear copy
#pragma unroll
        for (int it = 0; it < 4; ++it) {
          int q = it*THREADS + tid;
          __builtin_amdgcn_global_load_lds(
              (const __attribute__((address_space(1))) void*)(wsrc + (size_t)q*8),
              (__attribute__((address_space(3))) void*)&w_lds[(size_t)q*8],
              16, 0, 0);
        }
      }
      __syncthreads();   // drains vmcnt: staged x & w visible
      int dh = r / 3, dw = r - dh*3;
#pragma unroll
      for (int kh = 0; kh < 2; ++kh) {
        int cio = (kh*32 + lk*8)*2;   // byte offset of this lane's k-slice
        short8 a[4], bf[8];
#pragma unroll
        for (int m = 0; m < 4; ++m) {
          int co = wm*64 + m*16 + l15;
          int byte = (co*128 + cio) ^ ((co & 7) << 4);
          a[m] = *(const short8*)((const char*)w_lds + byte);
        }
#pragma unroll
        for (int f = 0; f < 8; ++f) {
          int row = (wn*2 + (f >> 2) + dh)*66 + ((f & 3)*16 + l15 + dw);
          int byte = (row*128 + cio) ^ ((row & 7) << 4);
          bf[f] = *(const short8*)((const char*)x_lds + byte);
        }
#pragma unroll
        for (int m = 0; m < 4; ++m)
#pragma unroll
          for (int f = 0; f < 8; ++f)
            acc[m][f] = __builtin_amdgcn_mfma_f32_16x16x32_bf16(a[m], bf[f], acc[m][f], 0, 0, 0);
      }
    }
  }

  // epilogue: D row = (lane>>4)*4 + j (co offset), col = lane&15 (w)
  int colane = (lane >> 4) * 4;
#pragma unroll
  for (int m = 0; m < 4; ++m) {
    int cob = wm*64 + m*16 + colane;
    float4 d4 = *(const float4*)&dm[b*256 + cob];
    float4 b4 = *(const float4*)&bias[cob];
#pragma unroll
    for (int f = 0; f < 8; ++f) {
      int h = h0 + wn*2 + (f >> 2);
      int wc = (f & 3)*16 + l15;
      float* op = out + ((size_t)(b*256 + cob)*64 + h)*64 + wc;
      op[0]     = acc[m][f][0] * d4.x + b4.x;
      op[4096]  = acc[m][f][1] * d4.y + b4.y;
      op[8192]  = acc[m][f][2] * d4.z + b4.z;
      op[12288] = acc[m][f][3] * d4.w + b4.w;
    }
  }
}

extern "C" void kernel_launch(void* const* d_in, const int* in_sizes, int n_in,
                              void* d_out, int out_size, void* d_ws, size_t ws_size,
                              hipStream_t stream) {
  const float* x      = (const float*)d_in[0];
  const float* style  = (const float*)d_in[1];
  const float* mw     = (const float*)d_in[2];
  const float* mb     = (const float*)d_in[3];
  const float* weight = (const float*)d_in[4];
  const float* bias   = (const float*)d_in[5];
  float* out = (float*)d_out;

  char* ws = (char*)d_ws;
  float* s_buf        = (float*)(ws);                           // 16 KB
  float* wsq          = (float*)(ws + 16384);                   // 256 KB
  float* dmod         = (float*)(ws + 16384 + 262144);          // 16 KB
  unsigned short* wbf = (unsigned short*)(ws + 294912);         // 1.125 MB
  unsigned short* xpd = (unsigned short*)(ws + 294912 + 1179648); // 34.03 MB

  k_style<<<16, 256, 0, stream>>>(style, mw, mb, s_buf);
  k_wprep<<<256, 256, 0, stream>>>(weight, wsq, wbf);
  k_demod<<<16, 256, 0, stream>>>(s_buf, wsq, dmod);
  k_pad<<<16*66, 256, 0, stream>>>(x, s_buf, xpd);
  k_conv<<<256, 512, 0, stream>>>(xpd, wbf, dmod, bias, out);
}